// Round 6
// baseline (281.455 us; speedup 1.0000x reference)
//
#include <hip/hip_runtime.h>

#define B_SZ 1024
#define H_SZ 2048
#define E_SZ 1024

typedef float  f32x4 __attribute__((ext_vector_type(4)));
typedef short  s16x8 __attribute__((ext_vector_type(8)));

__device__ __forceinline__ unsigned short f2bf(float f) {
    unsigned u = __float_as_uint(f);
    u = u + 0x7fffu + ((u >> 16) & 1u);   // RNE
    return (unsigned short)(u >> 16);
}
__device__ __forceinline__ float bf2f(unsigned short s) {
    return __uint_as_float(((unsigned)s) << 16);
}
__device__ __forceinline__ float sigm(float v) {
    return 1.0f / (1.0f + __expf(-v));
}

// ---------------------------------------------------- swizzling cast pass
// Converts fp32 [rows][K] to bf16 in MFMA fragment order:
//   dst16B-unit t = ((nt*K32 + ks)*8 + half*4 + i)*64 + lane
//   holds src[row][k..k+7],  row = nt*128 + half*64 + i*16 + (lane&15),
//                            k   = ks*32 + (lane>>4)*8.
// This is exactly the (A or B) fragment layout of mfma_f32_16x16x32_bf16
// as used by the verified LDS path in R5, so GEMMs can load fragments
// straight from global memory — no LDS, no barriers.
struct SwArgs {
    const float*    src[11];
    unsigned short* dst[11];
    int             log2K[11];
    int             nthr[11];
};

__global__ __launch_bounds__(256) void swcast_kernel(SwArgs a) {
    const int arr = blockIdx.y;
    const int t = blockIdx.x * 256 + threadIdx.x;
    if (t >= a.nthr[arr]) return;
    const int lg   = a.log2K[arr];
    const int lane = t & 63;
    const int u    = t >> 6;
    const int hj   = u & 7;
    const int v    = u >> 3;
    const int k32m = (1 << (lg - 5)) - 1;
    const int ks   = v & k32m;
    const int nt   = v >> (lg - 5);
    const int row  = (nt << 7) + ((hj >> 2) << 6) + ((hj & 3) << 4) + (lane & 15);
    const int k    = (ks << 5) + ((lane >> 4) << 3);
    const float* s = a.src[arr] + ((size_t)row << lg) + k;
    float4 v0 = *(const float4*)s;
    float4 v1 = *(const float4*)(s + 4);
    s16x8 o;
    o[0] = (short)f2bf(v0.x); o[1] = (short)f2bf(v0.y);
    o[2] = (short)f2bf(v0.z); o[3] = (short)f2bf(v0.w);
    o[4] = (short)f2bf(v1.x); o[5] = (short)f2bf(v1.y);
    o[6] = (short)f2bf(v1.z); o[7] = (short)f2bf(v1.w);
    *(s16x8*)(a.dst[arr] + (size_t)t * 8) = o;
}

// fragment load: 4 frags at base + ks*4096 + i*512 elements (16 B/lane)
#define LDF(dst, base, ks)                                                  \
    _Pragma("unroll") for (int _i = 0; _i < 4; ++_i)                        \
        dst[_i] = *(const s16x8*)((base) + (ks) * 4096 + _i * 512);

#define MF(aa, bb)                                                          \
    _Pragma("unroll") for (int _i = 0; _i < 4; ++_i)                        \
    _Pragma("unroll") for (int _j = 0; _j < 4; ++_j)                        \
        acc[_i][_j] = __builtin_amdgcn_mfma_f32_16x16x32_bf16(              \
            aa[_i], bb[_j], acc[_i][_j], 0, 0, 0);

// -------------------------------------- gate GEMMs: LDS-free, barrier-free
// 512 blocks, XCD swizzle as R5. Register ping-pong, prefetch distance 1;
// E-phase (32 ks) flows seamlessly into H-phase (64 ks) via transition
// prefetch. Per iteration-pair: 16 global_load_dwordx4 + 32 MFMA.
__global__ __launch_bounds__(256) void gates_kernel(
    const unsigned short* __restrict__ Xsw,
    const unsigned short* __restrict__ Hsw,
    const unsigned short* __restrict__ Wxsw,
    const unsigned short* __restrict__ Whsw,
    const float* __restrict__ bi, const float* __restrict__ bg,
    const float* __restrict__ bff, const float* __restrict__ bo,
    unsigned short* __restrict__ Z)
{
    const int t   = threadIdx.x;
    const int b   = blockIdx.x;
    const int xcd = b & 7;
    const int i_  = b >> 3;
    const int nt  = xcd * 8 + (i_ >> 3);
    const int mt  = i_ & 7;
    const int q   = nt >> 4;
    const int n0t = nt & 15;
    const int lane = t & 63, w = t >> 6;
    const int hm = w >> 1, hn = w & 1;

    const unsigned short* ax = Xsw + (size_t)(mt * 256 + hm * 4) * 512 + lane * 8;
    const unsigned short* bx = Wxsw + (size_t)q * H_SZ * E_SZ
                             + (size_t)(n0t * 256 + hn * 4) * 512 + lane * 8;
    const unsigned short* ah = Hsw + (size_t)(mt * 512 + hm * 4) * 512 + lane * 8;
    const unsigned short* bh = Whsw + (size_t)q * H_SZ * H_SZ
                             + (size_t)(n0t * 512 + hn * 4) * 512 + lane * 8;

    f32x4 acc[4][4] = {};
    s16x8 a0[4], b0[4], a1[4], b1[4];

    LDF(a0, ax, 0); LDF(b0, bx, 0);
    for (int ks = 0; ks < 30; ks += 2) {
        LDF(a1, ax, ks + 1); LDF(b1, bx, ks + 1);
        MF(a0, b0);
        LDF(a0, ax, ks + 2); LDF(b0, bx, ks + 2);
        MF(a1, b1);
    }
    LDF(a1, ax, 31); LDF(b1, bx, 31);
    MF(a0, b0);
    LDF(a0, ah, 0); LDF(b0, bh, 0);     // transition prefetch into H-phase
    MF(a1, b1);
    for (int ks = 0; ks < 62; ks += 2) {
        LDF(a1, ah, ks + 1); LDF(b1, bh, ks + 1);
        MF(a0, b0);
        LDF(a0, ah, ks + 2); LDF(b0, bh, ks + 2);
        MF(a1, b1);
    }
    LDF(a1, ah, 63); LDF(b1, bh, 63);
    MF(a0, b0);
    MF(a1, b1);

    const float* bias = (q == 0) ? bi : (q == 1) ? bg : (q == 2) ? bff : bo;
    const int m0 = mt * 128, n0 = n0t * 128;
    const int wr = hm << 6, wc = hn << 6;
    const int lr = lane & 15, rq = (lane >> 4) << 2;
    unsigned short* Zq = Z + (size_t)q * B_SZ * H_SZ;
#pragma unroll
    for (int i = 0; i < 4; ++i) {
#pragma unroll
        for (int j = 0; j < 4; ++j) {
            const int n = n0 + wc + j * 16 + lr;
            const float bv = bias[n];
#pragma unroll
            for (int r = 0; r < 4; ++r) {
                const int m = m0 + wr + i * 16 + rq + r;
                const float v = acc[i][j][r] + bv;
                const float a = (q == 1) ? tanhf(v) : sigm(v);
                Zq[(size_t)m * H_SZ + n] = f2bf(a);
            }
        }
    }
}

// ---------------------- cell update; writes h_new in swizzled A-layout too
__global__ __launch_bounds__(256) void cell_kernel(
    const unsigned short* __restrict__ Z, const float* __restrict__ c,
    float* __restrict__ c_out, float* __restrict__ h_out,
    unsigned short* __restrict__ Hnsw)
{
    const size_t BH = (size_t)B_SZ * H_SZ;
    const int t8 = blockIdx.x * 256 + threadIdx.x;   // 16-byte unit id
    const size_t base = (size_t)t8 * 8;

    s16x8 iu = *(const s16x8*)(Z + base);
    s16x8 gu = *(const s16x8*)(Z + BH + base);
    s16x8 fu = *(const s16x8*)(Z + 2 * BH + base);
    s16x8 ou = *(const s16x8*)(Z + 3 * BH + base);
    float4 c0 = *(const float4*)(c + base);
    float4 c1 = *(const float4*)(c + base + 4);
    const float cv[8] = {c0.x, c0.y, c0.z, c0.w, c1.x, c1.y, c1.z, c1.w};

    float cn[8], hn[8];
#pragma unroll
    for (int e = 0; e < 8; ++e) {
        cn[e] = bf2f((unsigned short)fu[e]) * cv[e]
              + bf2f((unsigned short)iu[e]) * bf2f((unsigned short)gu[e]);
        hn[e] = bf2f((unsigned short)ou[e]) * cn[e];
    }
    *(float4*)(c_out + base)     = make_float4(cn[0], cn[1], cn[2], cn[3]);
    *(float4*)(c_out + base + 4) = make_float4(cn[4], cn[5], cn[6], cn[7]);
    *(float4*)(h_out + base)     = make_float4(hn[0], hn[1], hn[2], hn[3]);
    *(float4*)(h_out + base + 4) = make_float4(hn[4], hn[5], hn[6], hn[7]);

    // swizzled write: m = batch row, hk = feature (k of the y-GEMM, K32=64)
    const int m  = (int)(base >> 11);
    const int hk = (int)(base & 2047);
    const int mt = m >> 7, half = (m >> 6) & 1, ii = (m >> 4) & 3, lr = m & 15;
    const int ks = hk >> 5, kq3 = (hk >> 3) & 3;
    const int lane2 = (kq3 << 4) | lr;
    const size_t toff = ((((size_t)mt * 64 + ks) * 8 + half * 4 + ii) * 64 + lane2) * 8;
    s16x8 hb;
#pragma unroll
    for (int e = 0; e < 8; ++e) hb[e] = (short)f2bf(hn[e]);
    *(s16x8*)(Hnsw + toff) = hb;
}

// --------------------------- y GEMM: LDS-free, split-K by 4 (256 blocks)
__global__ __launch_bounds__(256) void y_split_kernel(
    const unsigned short* __restrict__ Hnsw,
    const unsigned short* __restrict__ Whysw,
    float* __restrict__ part)
{
    const int t   = threadIdx.x;
    const int b   = blockIdx.x;
    const int xcd = b & 7;
    const int i_  = b >> 3;
    const int ns  = xcd * 4 + (i_ >> 3);
    const int mt  = i_ & 7;
    const int n0t = ns >> 2;
    const int s   = ns & 3;
    const int lane = t & 63, w = t >> 6;
    const int hm = w >> 1, hn = w & 1;

    const unsigned short* ay = Hnsw
        + (size_t)((mt * 64 + s * 16) * 8 + hm * 4) * 512 + lane * 8;
    const unsigned short* by = Whysw
        + (size_t)((n0t * 64 + s * 16) * 8 + hn * 4) * 512 + lane * 8;

    f32x4 acc[4][4] = {};
    s16x8 a0[4], b0[4], a1[4], b1[4];
    LDF(a0, ay, 0); LDF(b0, by, 0);
    for (int ks = 0; ks < 14; ks += 2) {
        LDF(a1, ay, ks + 1); LDF(b1, by, ks + 1);
        MF(a0, b0);
        LDF(a0, ay, ks + 2); LDF(b0, by, ks + 2);
        MF(a1, b1);
    }
    LDF(a1, ay, 15); LDF(b1, by, 15);
    MF(a0, b0);
    MF(a1, b1);

    const int m0 = mt * 128, n0 = n0t * 128;
    const int wr = hm << 6, wc = hn << 6;
    const int lr = lane & 15, rq = (lane >> 4) << 2;
    float* P = part + (size_t)s * B_SZ * E_SZ;
#pragma unroll
    for (int i = 0; i < 4; ++i) {
#pragma unroll
        for (int j = 0; j < 4; ++j) {
            const int n = n0 + wc + j * 16 + lr;
#pragma unroll
            for (int r = 0; r < 4; ++r) {
                const int m = m0 + wr + i * 16 + rq + r;
                P[(size_t)m * E_SZ + n] = acc[i][j][r];
            }
        }
    }
}

__global__ __launch_bounds__(256) void y_reduce_kernel(
    const float* __restrict__ part, const float* __restrict__ by,
    float* __restrict__ yout)
{
    const size_t BE = (size_t)B_SZ * E_SZ;
    const int idx = (blockIdx.x * 256 + threadIdx.x) * 4;
    float4 a = *(const float4*)(part + idx);
    float4 b2 = *(const float4*)(part + BE + idx);
    float4 c2 = *(const float4*)(part + 2 * BE + idx);
    float4 d2 = *(const float4*)(part + 3 * BE + idx);
    const int col = idx & (E_SZ - 1);
    float4 bv = *(const float4*)(by + col);
    float4 o;
    o.x = tanhf(a.x + b2.x + c2.x + d2.x + bv.x);
    o.y = tanhf(a.y + b2.y + c2.y + d2.y + bv.y);
    o.z = tanhf(a.z + b2.z + c2.z + d2.z + bv.z);
    o.w = tanhf(a.w + b2.w + c2.w + d2.w + bv.w);
    *(float4*)(yout + idx) = o;
}

// ---------------------------------------------------------------- launch
extern "C" void kernel_launch(void* const* d_in, const int* in_sizes, int n_in,
                              void* d_out, int out_size, void* d_ws, size_t ws_size,
                              hipStream_t stream) {
    const float* x   = (const float*)d_in[0];
    const float* c   = (const float*)d_in[1];
    const float* h   = (const float*)d_in[2];
    const float* Wxi = (const float*)d_in[3];
    const float* Whi = (const float*)d_in[4];
    const float* Bi  = (const float*)d_in[5];
    const float* Wxg = (const float*)d_in[6];
    const float* Whg = (const float*)d_in[7];
    const float* Bg  = (const float*)d_in[8];
    const float* Wxf = (const float*)d_in[9];
    const float* Whf = (const float*)d_in[10];
    const float* Bf  = (const float*)d_in[11];
    const float* Wxo = (const float*)d_in[12];
    const float* Who = (const float*)d_in[13];
    const float* Bo  = (const float*)d_in[14];
    const float* Why = (const float*)d_in[15];
    const float* By  = (const float*)d_in[16];

    const size_t BE = (size_t)B_SZ * E_SZ, BH = (size_t)B_SZ * H_SZ;
    const size_t HE = (size_t)H_SZ * E_SZ, HH = (size_t)H_SZ * H_SZ;
    const size_t EH = (size_t)E_SZ * H_SZ;

    unsigned short* ws    = (unsigned short*)d_ws;
    unsigned short* Xsw   = ws;                 // BE
    unsigned short* Hsw   = Xsw + BE;           // BH
    unsigned short* Wxsw  = Hsw + BH;           // 4*HE
    unsigned short* Whsw  = Wxsw + 4 * HE;      // 4*HH
    unsigned short* Whysw = Whsw + 4 * HH;      // EH
    unsigned short* Z     = Whysw + EH;         // 4*BH bf16 (16 MB); later fp32 y-partials
    unsigned short* Hnsw  = Z + 4 * BH;         // BH

    SwArgs sa;
    sa.src[0]  = x;   sa.dst[0]  = Xsw;          sa.log2K[0]  = 10; sa.nthr[0]  = (int)(BE / 8);
    sa.src[1]  = h;   sa.dst[1]  = Hsw;          sa.log2K[1]  = 11; sa.nthr[1]  = (int)(BH / 8);
    sa.src[2]  = Wxi; sa.dst[2]  = Wxsw;         sa.log2K[2]  = 10; sa.nthr[2]  = (int)(HE / 8);
    sa.src[3]  = Wxg; sa.dst[3]  = Wxsw + HE;    sa.log2K[3]  = 10; sa.nthr[3]  = (int)(HE / 8);
    sa.src[4]  = Wxf; sa.dst[4]  = Wxsw + 2*HE;  sa.log2K[4]  = 10; sa.nthr[4]  = (int)(HE / 8);
    sa.src[5]  = Wxo; sa.dst[5]  = Wxsw + 3*HE;  sa.log2K[5]  = 10; sa.nthr[5]  = (int)(HE / 8);
    sa.src[6]  = Whi; sa.dst[6]  = Whsw;         sa.log2K[6]  = 11; sa.nthr[6]  = (int)(HH / 8);
    sa.src[7]  = Whg; sa.dst[7]  = Whsw + HH;    sa.log2K[7]  = 11; sa.nthr[7]  = (int)(HH / 8);
    sa.src[8]  = Whf; sa.dst[8]  = Whsw + 2*HH;  sa.log2K[8]  = 11; sa.nthr[8]  = (int)(HH / 8);
    sa.src[9]  = Who; sa.dst[9]  = Whsw + 3*HH;  sa.log2K[9]  = 11; sa.nthr[9]  = (int)(HH / 8);
    sa.src[10] = Why; sa.dst[10] = Whysw;        sa.log2K[10] = 11; sa.nthr[10] = (int)(EH / 8);

    hipLaunchKernelGGL(swcast_kernel, dim3(2048, 11), dim3(256), 0, stream, sa);
    hipLaunchKernelGGL(gates_kernel, dim3(512), dim3(256), 0, stream,
                       Xsw, Hsw, Wxsw, Whsw, Bi, Bg, Bf, Bo, Z);

    float* y_out = (float*)d_out;
    float* c_out = y_out + BE;
    float* h_out = c_out + BH;
    hipLaunchKernelGGL(cell_kernel, dim3((unsigned)(BH / 2048)), dim3(256), 0, stream,
                       Z, c, c_out, h_out, Hnsw);

    float* ypart = (float*)Z;   // Z dead after cell_kernel
    hipLaunchKernelGGL(y_split_kernel, dim3(256), dim3(256), 0, stream,
                       Hnsw, Whysw, ypart);
    hipLaunchKernelGGL(y_reduce_kernel, dim3((unsigned)(BE / 1024)), dim3(256), 0, stream,
                       ypart, By, y_out);
}